// Round 9
// baseline (700.792 us; speedup 1.0000x reference)
//
#include <hip/hip_runtime.h>

#define DD 128
#define ROWS 16      // batch rows per block (256 threads, 4 waves)

__device__ __forceinline__ float gsum16(float s) {
    s += __shfl_xor(s, 1, 16);
    s += __shfl_xor(s, 2, 16);
    s += __shfl_xor(s, 4, 16);
    s += __shfl_xor(s, 8, 16);
    return s;
}

__device__ __forceinline__ float dot8(const float4& a, const float4& b,
                                      const float4& c, const float4& d) {
    float s = a.x * c.x;
    s = fmaf(a.y, c.y, s); s = fmaf(a.z, c.z, s); s = fmaf(a.w, c.w, s);
    s = fmaf(b.x, d.x, s); s = fmaf(b.y, d.y, s); s = fmaf(b.z, d.z, s);
    s = fmaf(b.w, d.w, s);
    return s;
}

__global__ __launch_bounds__(256, 4)
void MATE_fused_kernel(const float* __restrict__ user,
                       const float* __restrict__ cur_month,
                       const float* __restrict__ cur_day,
                       const float* __restrict__ cur_date,
                       const float* __restrict__ cur_hour,
                       const float* __restrict__ month_emb,
                       const float* __restrict__ day_emb,
                       const float* __restrict__ date_emb,
                       const float* __restrict__ hour_emb,
                       const float* __restrict__ Wg,
                       const float* __restrict__ Wm,
                       const float* __restrict__ Wd,
                       const float* __restrict__ Wt,
                       const float* __restrict__ Wh,
                       float* __restrict__ out)
{
    // 40 KB: regions 0..3 = uM,uD,uT,uH projections; region 4 doubles as
    // user staging (phase A/B) then gate projection uW (phase C).
    __shared__ float p_lds[5 * ROWS * DD];
    float* const u_lds = p_lds + 4 * ROWS * DD;

    const int t  = threadIdx.x;
    const int b0 = blockIdx.x * ROWS;

    // ---- Phase A: user rows -> LDS ----
    #pragma unroll
    for (int i = 0; i < ROWS * DD / 256; ++i)
        u_lds[i * 256 + t] = user[(size_t)b0 * DD + i * 256 + t];
    __syncthreads();

    // ---- Phase B: 5 projections, 8-row amortization per W element ----
    {
        const int e  = t & 127;
        const int rh = (t >> 7) * 8;
        float accM[8] = {0}, accD[8] = {0}, accT[8] = {0}, accH[8] = {0}, accG[8] = {0};
        for (int d4 = 0; d4 < DD; d4 += 4) {
            float4 u4[8];
            #pragma unroll
            for (int r = 0; r < 8; ++r)
                u4[r] = *(const float4*)&u_lds[(rh + r) * DD + d4];
            #pragma unroll
            for (int dd = 0; dd < 4; ++dd) {
                const int d = d4 + dd;
                const float wm = Wm[d * DD + e];
                const float wd = Wd[d * DD + e];
                const float wt = Wt[d * DD + e];
                const float wh = Wh[d * DD + e];
                const float wg = Wg[d * DD + e];
                #pragma unroll
                for (int r = 0; r < 8; ++r) {
                    const float u = (dd == 0) ? u4[r].x : (dd == 1) ? u4[r].y
                                  : (dd == 2) ? u4[r].z : u4[r].w;
                    accM[r] = fmaf(u, wm, accM[r]);
                    accD[r] = fmaf(u, wd, accD[r]);
                    accT[r] = fmaf(u, wt, accT[r]);
                    accH[r] = fmaf(u, wh, accH[r]);
                    accG[r] = fmaf(u, wg, accG[r]);
                }
            }
        }
        #pragma unroll
        for (int r = 0; r < 8; ++r) {
            p_lds[(0 * ROWS + rh + r) * DD + e] = accM[r];
            p_lds[(1 * ROWS + rh + r) * DD + e] = accD[r];
            p_lds[(2 * ROWS + rh + r) * DD + e] = accT[r];
            p_lds[(3 * ROWS + rh + r) * DD + e] = accH[r];
        }
        __syncthreads();   // everyone done READING u_lds before overwrite
        #pragma unroll
        for (int r = 0; r < 8; ++r)
            p_lds[(4 * ROWS + rh + r) * DD + e] = accG[r];
    }
    __syncthreads();

    // ---- Phase C: one wave per batch row, 4 branches in parallel ----
    // lane group g = branch; 16 lanes x 8 dims = 128 dims per branch.
    const int w = t >> 6, lane = t & 63;
    const int g = lane >> 4, sub = lane & 15, d0 = sub * 8;
    const float scale = 0.08838834764831845f;   // 1/sqrt(128)

    const float* curp = (g == 0) ? cur_month : (g == 1) ? cur_day
                       : (g == 2) ? cur_date : cur_hour;
    const float* embp = (g == 0) ? month_emb : (g == 1) ? day_emb
                       : (g == 2) ? date_emb : hour_emb;
    const int    Sg   = (g == 0) ? 11 : (g == 1) ? 6 : (g == 2) ? 30 : 23;

    for (int i = 0; i < 4; ++i) {
        const int r = w * 4 + i;
        const int b = b0 + r;

        const float* up = &p_lds[(g * ROWS + r) * DD + d0];
        const float4 ua = *(const float4*)up;
        const float4 ub = *(const float4*)(up + 4);

        const float* cp = curp + (size_t)b * DD + d0;
        const float4 ca = *(const float4*)cp;
        const float4 cb = *(const float4*)(cp + 4);

        float4 qa, qb;
        qa.x = ca.x * ua.x; qa.y = ca.y * ua.y; qa.z = ca.z * ua.z; qa.w = ca.w * ua.w;
        qb.x = cb.x * ub.x; qb.y = cb.y * ub.y; qb.z = cb.z * ub.z; qb.w = cb.w * ub.w;

        const float* ebase = embp + (size_t)b * Sg * DD + d0;

        float  l  = 0.f;
        float4 aa = make_float4(0.f, 0.f, 0.f, 0.f);
        float4 ab = make_float4(0.f, 0.f, 0.f, 0.f);

        // Uniform 30-iteration loop: groups with S < 30 re-read their last
        // row (L1 hit) and zero p — no exec divergence, fully unrollable.
        #pragma unroll
        for (int k = 0; k < 30; ++k) {
            const int kk = (k < Sg) ? k : (Sg - 1);
            const float* ep = ebase + kk * DD;
            const float4 ea = *(const float4*)ep;
            const float4 eb = *(const float4*)(ep + 4);
            float4 ga, gb;
            ga.x = ea.x * ua.x; ga.y = ea.y * ua.y; ga.z = ea.z * ua.z; ga.w = ea.w * ua.w;
            gb.x = eb.x * ub.x; gb.y = eb.y * ub.y; gb.z = eb.z * ub.z; gb.w = eb.w * ub.w;

            float s = gsum16(dot8(qa, qb, ga, gb));
            float p = __expf(s * scale);
            p = (k < Sg) ? p : 0.f;
            l += p;
            aa.x = fmaf(p, ga.x, aa.x); aa.y = fmaf(p, ga.y, aa.y);
            aa.z = fmaf(p, ga.z, aa.z); aa.w = fmaf(p, ga.w, aa.w);
            ab.x = fmaf(p, gb.x, ab.x); ab.y = fmaf(p, gb.y, ab.y);
            ab.z = fmaf(p, gb.z, ab.z); ab.w = fmaf(p, gb.w, ab.w);
        }
        // self row (q appended to kv)
        {
            float s = gsum16(dot8(qa, qb, qa, qb));
            float p = __expf(s * scale);
            l += p;
            aa.x = fmaf(p, qa.x, aa.x); aa.y = fmaf(p, qa.y, aa.y);
            aa.z = fmaf(p, qa.z, aa.z); aa.w = fmaf(p, qa.w, aa.w);
            ab.x = fmaf(p, qb.x, ab.x); ab.y = fmaf(p, qb.y, ab.y);
            ab.z = fmaf(p, qb.z, ab.z); ab.w = fmaf(p, qb.w, ab.w);
        }
        const float inv = 1.f / l;
        float4 oa, ob;
        oa.x = aa.x * inv; oa.y = aa.y * inv; oa.z = aa.z * inv; oa.w = aa.w * inv;
        ob.x = ab.x * inv; ob.y = ab.y * inv; ob.z = ab.z * inv; ob.w = ab.w * inv;

        // sigmoid gate: a_g = sigmoid(uW . o_g), then out = sum_g a_g o_g
        const float* wp = &p_lds[(4 * ROWS + r) * DD + d0];
        const float4 wa = *(const float4*)wp;
        const float4 wb = *(const float4*)(wp + 4);
        const float sg = gsum16(dot8(wa, wb, oa, ob));
        const float ag = 1.f / (1.f + __expf(-sg));

        float4 va, vb;
        va.x = ag * oa.x; va.y = ag * oa.y; va.z = ag * oa.z; va.w = ag * oa.w;
        vb.x = ag * ob.x; vb.y = ag * ob.y; vb.z = ag * ob.z; vb.w = ag * ob.w;

        // sum across the 4 branch groups (butterfly over lane bits 4,5)
        #define XG(f) f += __shfl_xor(f, 16, 64); f += __shfl_xor(f, 32, 64);
        XG(va.x) XG(va.y) XG(va.z) XG(va.w)
        XG(vb.x) XG(vb.y) XG(vb.z) XG(vb.w)
        #undef XG

        if (g == 0) {
            float* op = out + (size_t)b * DD + d0;
            *(float4*)op       = va;
            *(float4*)(op + 4) = vb;
        }
    }
}

extern "C" void kernel_launch(void* const* d_in, const int* in_sizes, int n_in,
                              void* d_out, int out_size, void* d_ws, size_t ws_size,
                              hipStream_t stream) {
    const float* user      = (const float*)d_in[0];
    const float* cur_month = (const float*)d_in[1];
    const float* cur_day   = (const float*)d_in[2];
    const float* cur_date  = (const float*)d_in[3];
    const float* cur_hour  = (const float*)d_in[4];
    const float* month_emb = (const float*)d_in[5];
    const float* day_emb   = (const float*)d_in[6];
    const float* date_emb  = (const float*)d_in[7];
    const float* hour_emb  = (const float*)d_in[8];
    const float* Wg        = (const float*)d_in[9];
    const float* Wm        = (const float*)d_in[10];
    const float* Wd        = (const float*)d_in[11];
    const float* Wt        = (const float*)d_in[12];
    const float* Wh        = (const float*)d_in[13];
    float* out = (float*)d_out;

    const int B    = in_sizes[0] / DD;   // 16384
    const int grid = B / ROWS;           // 1024 blocks = 4 per CU

    MATE_fused_kernel<<<grid, 256, 0, stream>>>(
        user, cur_month, cur_day, cur_date, cur_hour,
        month_emb, day_emb, date_emb, hour_emb,
        Wg, Wm, Wd, Wt, Wh, out);
}

// Round 11
// 698.236 us; speedup vs baseline: 1.0037x; 1.0037x over previous
//
#include <hip/hip_runtime.h>

#define DD 128
#define ROWS 32       // batch rows per block (512 threads, 8 waves)
#define THREADS 512

__device__ __forceinline__ float gsum16(float s) {
    s += __shfl_xor(s, 1, 16);
    s += __shfl_xor(s, 2, 16);
    s += __shfl_xor(s, 4, 16);
    s += __shfl_xor(s, 8, 16);
    return s;
}

__device__ __forceinline__ float dot8(const float4& a, const float4& b,
                                      const float4& c, const float4& d) {
    float s = a.x * c.x;
    s = fmaf(a.y, c.y, s); s = fmaf(a.z, c.z, s); s = fmaf(a.w, c.w, s);
    s = fmaf(b.x, d.x, s); s = fmaf(b.y, d.y, s); s = fmaf(b.z, d.z, s);
    s = fmaf(b.w, d.w, s);
    return s;
}

// 512 threads, 80 KB LDS -> 2 blocks/CU (160 KB), 16 waves/CU (50% occ),
// 128-VGPR budget (4 waves/SIMD) -> Phase B's ~72 live regs fit, NO SPILL.
// (round-9 lesson: (256,4) capped VGPRs at 64 -> 470 MB of scratch traffic)
__global__ __launch_bounds__(THREADS, 4)
void MATE_fused_kernel(const float* __restrict__ user,
                       const float* __restrict__ cur_month,
                       const float* __restrict__ cur_day,
                       const float* __restrict__ cur_date,
                       const float* __restrict__ cur_hour,
                       const float* __restrict__ month_emb,
                       const float* __restrict__ day_emb,
                       const float* __restrict__ date_emb,
                       const float* __restrict__ hour_emb,
                       const float* __restrict__ Wg,
                       const float* __restrict__ Wm,
                       const float* __restrict__ Wd,
                       const float* __restrict__ Wt,
                       const float* __restrict__ Wh,
                       float* __restrict__ out)
{
    // regions 0..3 = uM,uD,uT,uH; region 4 doubles as user staging then uW.
    __shared__ float p_lds[5 * ROWS * DD];   // 80 KB
    float* const u_lds = p_lds + 4 * ROWS * DD;

    const int t  = threadIdx.x;
    const int b0 = blockIdx.x * ROWS;

    // ---- Phase A: user rows -> LDS ----
    #pragma unroll
    for (int i = 0; i < ROWS * DD / THREADS; ++i)
        u_lds[i * THREADS + t] = user[(size_t)b0 * DD + i * THREADS + t];
    __syncthreads();

    // ---- Phase B: 5 projections, 8-row amortization per W element ----
    {
        const int e  = t & 127;
        const int rh = (t >> 7) * 8;   // 4 groups x 8 rows = 32 rows
        float accM[8] = {0}, accD[8] = {0}, accT[8] = {0}, accH[8] = {0}, accG[8] = {0};
        for (int d4 = 0; d4 < DD; d4 += 4) {
            float4 u4[8];
            #pragma unroll
            for (int r = 0; r < 8; ++r)
                u4[r] = *(const float4*)&u_lds[(rh + r) * DD + d4];
            #pragma unroll
            for (int dd = 0; dd < 4; ++dd) {
                const int d = d4 + dd;
                const float wm = Wm[d * DD + e];
                const float wd = Wd[d * DD + e];
                const float wt = Wt[d * DD + e];
                const float wh = Wh[d * DD + e];
                const float wg = Wg[d * DD + e];
                #pragma unroll
                for (int r = 0; r < 8; ++r) {
                    const float u = (dd == 0) ? u4[r].x : (dd == 1) ? u4[r].y
                                  : (dd == 2) ? u4[r].z : u4[r].w;
                    accM[r] = fmaf(u, wm, accM[r]);
                    accD[r] = fmaf(u, wd, accD[r]);
                    accT[r] = fmaf(u, wt, accT[r]);
                    accH[r] = fmaf(u, wh, accH[r]);
                    accG[r] = fmaf(u, wg, accG[r]);
                }
            }
        }
        #pragma unroll
        for (int r = 0; r < 8; ++r) {
            p_lds[(0 * ROWS + rh + r) * DD + e] = accM[r];
            p_lds[(1 * ROWS + rh + r) * DD + e] = accD[r];
            p_lds[(2 * ROWS + rh + r) * DD + e] = accT[r];
            p_lds[(3 * ROWS + rh + r) * DD + e] = accH[r];
        }
        __syncthreads();   // all reads of u_lds done before overwrite
        #pragma unroll
        for (int r = 0; r < 8; ++r)
            p_lds[(4 * ROWS + rh + r) * DD + e] = accG[r];
    }
    __syncthreads();

    // ---- Phase C: one wave per batch row, 4 branches in parallel ----
    const int w = t >> 6, lane = t & 63;
    const int g = lane >> 4, sub = lane & 15, d0 = sub * 8;
    const float scale = 0.08838834764831845f;   // 1/sqrt(128)

    const float* curp = (g == 0) ? cur_month : (g == 1) ? cur_day
                       : (g == 2) ? cur_date : cur_hour;
    const float* embp = (g == 0) ? month_emb : (g == 1) ? day_emb
                       : (g == 2) ? date_emb : hour_emb;
    const int    Sg   = (g == 0) ? 11 : (g == 1) ? 6 : (g == 2) ? 30 : 23;

    for (int i = 0; i < 4; ++i) {
        const int r = w * 4 + i;        // 8 waves x 4 rows = 32 rows
        const int b = b0 + r;

        const float* up = &p_lds[(g * ROWS + r) * DD + d0];
        const float4 ua = *(const float4*)up;
        const float4 ub = *(const float4*)(up + 4);

        const float* cp = curp + (size_t)b * DD + d0;
        const float4 ca = *(const float4*)cp;
        const float4 cb = *(const float4*)(cp + 4);

        float4 qa, qb;
        qa.x = ca.x * ua.x; qa.y = ca.y * ua.y; qa.z = ca.z * ua.z; qa.w = ca.w * ua.w;
        qb.x = cb.x * ub.x; qb.y = cb.y * ub.y; qb.z = cb.z * ub.z; qb.w = cb.w * ub.w;

        const float* ebase = embp + (size_t)b * Sg * DD + d0;

        float  l  = 0.f;
        float4 aa = make_float4(0.f, 0.f, 0.f, 0.f);
        float4 ab = make_float4(0.f, 0.f, 0.f, 0.f);

        // Uniform 30-iteration loop: groups with S < 30 re-read their last
        // row (L1 hit) and zero p — no exec divergence, fully unrollable.
        #pragma unroll
        for (int k = 0; k < 30; ++k) {
            const int kk = (k < Sg) ? k : (Sg - 1);
            const float* ep = ebase + kk * DD;
            const float4 ea = *(const float4*)ep;
            const float4 eb = *(const float4*)(ep + 4);
            float4 ga, gb;
            ga.x = ea.x * ua.x; ga.y = ea.y * ua.y; ga.z = ea.z * ua.z; ga.w = ea.w * ua.w;
            gb.x = eb.x * ub.x; gb.y = eb.y * ub.y; gb.z = eb.z * ub.z; gb.w = eb.w * ub.w;

            float s = gsum16(dot8(qa, qb, ga, gb));
            float p = __expf(s * scale);
            p = (k < Sg) ? p : 0.f;
            l += p;
            aa.x = fmaf(p, ga.x, aa.x); aa.y = fmaf(p, ga.y, aa.y);
            aa.z = fmaf(p, ga.z, aa.z); aa.w = fmaf(p, ga.w, aa.w);
            ab.x = fmaf(p, gb.x, ab.x); ab.y = fmaf(p, gb.y, ab.y);
            ab.z = fmaf(p, gb.z, ab.z); ab.w = fmaf(p, gb.w, ab.w);
        }
        // self row (q appended to kv)
        {
            float s = gsum16(dot8(qa, qb, qa, qb));
            float p = __expf(s * scale);
            l += p;
            aa.x = fmaf(p, qa.x, aa.x); aa.y = fmaf(p, qa.y, aa.y);
            aa.z = fmaf(p, qa.z, aa.z); aa.w = fmaf(p, qa.w, aa.w);
            ab.x = fmaf(p, qb.x, ab.x); ab.y = fmaf(p, qb.y, ab.y);
            ab.z = fmaf(p, qb.z, ab.z); ab.w = fmaf(p, qb.w, ab.w);
        }
        const float inv = 1.f / l;
        float4 oa, ob;
        oa.x = aa.x * inv; oa.y = aa.y * inv; oa.z = aa.z * inv; oa.w = aa.w * inv;
        ob.x = ab.x * inv; ob.y = ab.y * inv; ob.z = ab.z * inv; ob.w = ab.w * inv;

        // sigmoid gate: a_g = sigmoid(uW . o_g), then out = sum_g a_g o_g
        const float* wp = &p_lds[(4 * ROWS + r) * DD + d0];
        const float4 wa = *(const float4*)wp;
        const float4 wb = *(const float4*)(wp + 4);
        const float sg = gsum16(dot8(wa, wb, oa, ob));
        const float ag = 1.f / (1.f + __expf(-sg));

        float4 va, vb;
        va.x = ag * oa.x; va.y = ag * oa.y; va.z = ag * oa.z; va.w = ag * oa.w;
        vb.x = ag * ob.x; vb.y = ag * ob.y; vb.z = ag * ob.z; vb.w = ag * ob.w;

        // sum across the 4 branch groups (butterfly over lane bits 4,5)
        #define XG(f) f += __shfl_xor(f, 16, 64); f += __shfl_xor(f, 32, 64);
        XG(va.x) XG(va.y) XG(va.z) XG(va.w)
        XG(vb.x) XG(vb.y) XG(vb.z) XG(vb.w)
        #undef XG

        if (g == 0) {
            float* op = out + (size_t)b * DD + d0;
            *(float4*)op       = va;
            *(float4*)(op + 4) = vb;
        }
    }
}

extern "C" void kernel_launch(void* const* d_in, const int* in_sizes, int n_in,
                              void* d_out, int out_size, void* d_ws, size_t ws_size,
                              hipStream_t stream) {
    const float* user      = (const float*)d_in[0];
    const float* cur_month = (const float*)d_in[1];
    const float* cur_day   = (const float*)d_in[2];
    const float* cur_date  = (const float*)d_in[3];
    const float* cur_hour  = (const float*)d_in[4];
    const float* month_emb = (const float*)d_in[5];
    const float* day_emb   = (const float*)d_in[6];
    const float* date_emb  = (const float*)d_in[7];
    const float* hour_emb  = (const float*)d_in[8];
    const float* Wg        = (const float*)d_in[9];
    const float* Wm        = (const float*)d_in[10];
    const float* Wd        = (const float*)d_in[11];
    const float* Wt        = (const float*)d_in[12];
    const float* Wh        = (const float*)d_in[13];
    float* out = (float*)d_out;

    const int B    = in_sizes[0] / DD;    // 16384
    const int grid = B / ROWS;            // 512 blocks = 2 per CU exactly

    MATE_fused_kernel<<<grid, THREADS, 0, stream>>>(
        user, cur_month, cur_day, cur_date, cur_hour,
        month_emb, day_emb, date_emb, hour_emb,
        Wg, Wm, Wd, Wt, Wh, out);
}